// Round 11
// baseline (73.845 us; speedup 1.0000x reference)
//
#include <hip/hip_runtime.h>

#define NQ 12
#define NT 256   // 4 waves per block; one batch element per block; 16 amps/thread

typedef float v2 __attribute__((ext_vector_type(2)));

// ---------- GF(2)-linear index machinery (HW-verified R4..R10) ----------
__host__ __device__ constexpr int par12(int v) {
    v ^= v >> 8; v ^= v >> 4; v ^= v >> 2; v ^= v >> 1; return v & 1;
}
// LDS slot: SL'(i) = i ^ ((i>>4)&15). Linear; preserves bits 10-11 (wave id);
// all four era patterns bank-pair-injective per 16-lane phase (R10: conflicts=0).

// scalar complex mul: (or,oi) = (cr,ci) * (ar,ai)   [1 mul + 1 fma per component]
#define CMUL(orr, oii, cr, ci, ar, ai)                                  \
    { float tr_ = (cr) * (ar) - (ci) * (ai);                            \
      float ti_ = (cr) * (ai) + (ci) * (ar);                            \
      (orr) = tr_; (oii) = ti_; }

__global__ __launch_bounds__(NT, 4) void qsim_kernel(
    const float* __restrict__ x,   // (B, 12) fp32
    const float* __restrict__ w,   // (2, 12, 3) fp32
    float* __restrict__ out)       // (B, 12) fp32
{
    __shared__ v2 sc[4096];                       // 32 KB state scratch
    __shared__ __align__(16) float fm[2][NQ][8];  // fused U = Rot*RY
    __shared__ float red[4][NQ];

    const int t  = threadIdx.x;
    const int L  = t & 63;
    const int Wv = t >> 6;        // wave id 0..3
    const int b  = blockIdx.x;

    // ---- fused gate matrices U = Rot(phi,theta,omega) * RY(x_q) ----
    if (t < 2 * NQ) {
        int l = t / NQ, q = t % NQ;
        float hy = 0.5f * x[b * NQ + q];
        float cy = cosf(hy), sy = sinf(hy);
        const float* wp = w + (l * NQ + q) * 3;
        float phi = wp[0], the = wp[1], om = wp[2];
        float c = cosf(0.5f * the), s = sinf(0.5f * the);
        float al = 0.5f * (phi + om), be = 0.5f * (phi - om);
        float ca = cosf(al), sa = sinf(al), cb = cosf(be), sb = sinf(be);
        float r00r =  ca * c, r00i = -sa * c;
        float r01r = -cb * s, r01i = -sb * s;
        float r10r =  cb * s, r10i = -sb * s;
        float r11r =  ca * c, r11i =  sa * c;
        float* m = fm[l][q];
        m[0] =  r00r * cy + r01r * sy;  m[1] =  r00i * cy + r01i * sy;  // U00
        m[2] = -r00r * sy + r01r * cy;  m[3] = -r00i * sy + r01i * cy;  // U01
        m[4] =  r10r * cy + r11r * sy;  m[5] =  r10i * cy + r11i * sy;  // U10
        m[6] = -r10r * sy + r11r * cy;  m[7] = -r10i * sy + r11i * cy;  // U11
    }

    // ---- era slot bases under SL'(i) = i ^ ((i>>4)&15) ----
    const int g0    = (Wv << 10) | (L << 4);
    const int rbase = g0 ^ (L & 15);                       // T1 write: ^ r
    const int q1i   = (Wv << 10) | ((L >> 4) << 8) | (L & 15);
    // T1 read / T2 write: slot = q1i ^ (r<<4) ^ r
    const int q2t   = (Wv << 6) | L;
    const int q2s   = q2t ^ (L >> 4) ^ ((Wv & 3) << 2);    // T2 read: ^ (r<<8)
    const int L0 = L & 1, Wv0 = Wv & 1, Wv1 = Wv >> 1;
    // epilogue sign-flip masks per lane bit
    unsigned sm0 = (L & 1)  ? 0x80000000u : 0u;
    unsigned sm1 = (L & 2)  ? 0x80000000u : 0u;
    unsigned sm2 = (L & 4)  ? 0x80000000u : 0u;
    unsigned sm3 = (L & 8)  ? 0x80000000u : 0u;
    unsigned sm4 = (L & 16) ? 0x80000000u : 0u;
    unsigned sm5 = (L & 32) ? 0x80000000u : 0u;

    __syncthreads();   // fm ready  [barrier 1]

    // ==== post-ring1 state built DIRECTLY in registers (R9-verified algebra)
    // amp(i) = prod_q v_q[x_{11-q}], x = ringInv(i), i = (Wv<<10)|(L<<4)|r.
    float Ar[16], Ai[16];
    {
        const float* m7 = &fm[0][7][((L ^ (L >> 1)) & 1) ? 4 : 0];
        float Cr = m7[0], Ci = m7[1];
        const float* m6 = &fm[0][6][(((L >> 1) ^ (L >> 2)) & 1) ? 4 : 0];
        CMUL(Cr, Ci, m6[0], m6[1], Cr, Ci);
        const float* m5 = &fm[0][5][(((L >> 2) ^ (L >> 3)) & 1) ? 4 : 0];
        CMUL(Cr, Ci, m5[0], m5[1], Cr, Ci);
        const float* m4 = &fm[0][4][(((L >> 3) ^ (L >> 4)) & 1) ? 4 : 0];
        CMUL(Cr, Ci, m4[0], m4[1], Cr, Ci);
        const float* m3 = &fm[0][3][(((L >> 4) ^ (L >> 5)) & 1) ? 4 : 0];
        CMUL(Cr, Ci, m3[0], m3[1], Cr, Ci);
        const float* m2 = &fm[0][2][(((L >> 5) ^ Wv0) & 1) ? 4 : 0];
        CMUL(Cr, Ci, m2[0], m2[1], Cr, Ci);
        // A2[r0] = C * v1[Wv0^Wv1^r0] * v0[Wv1^r0]
        const float* v1a = &fm[0][1][(Wv0 ^ Wv1) ? 4 : 0];
        const float* v1b = &fm[0][1][(Wv0 ^ Wv1) ? 0 : 4];
        const float* v0a = &fm[0][0][Wv1 ? 4 : 0];
        const float* v0b = &fm[0][0][Wv1 ? 0 : 4];
        float e0r, e0i, e1r, e1i;
        CMUL(e0r, e0i, v1a[0], v1a[1], v0a[0], v0a[1]);
        CMUL(e0r, e0i, Cr, Ci, e0r, e0i);
        CMUL(e1r, e1i, v1b[0], v1b[1], v0b[0], v0b[1]);
        CMUL(e1r, e1i, Cr, Ci, e1r, e1i);
        // A4: x v11[r0^r1]
        float w0r = fm[0][11][0], w0i = fm[0][11][1];
        float w1r = fm[0][11][4], w1i = fm[0][11][5];
        float A4r[4], A4i[4];
        CMUL(A4r[0], A4i[0], w0r, w0i, e0r, e0i);   // r1=0, r0=0
        CMUL(A4r[1], A4i[1], w1r, w1i, e1r, e1i);   // r1=0, r0=1
        CMUL(A4r[2], A4i[2], w1r, w1i, e0r, e0i);   // r1=1, r0=0
        CMUL(A4r[3], A4i[3], w0r, w0i, e1r, e1i);   // r1=1, r0=1
        // A8: x v10[r1^r2]
        float f0r = fm[0][10][0], f0i = fm[0][10][1];
        float f1r = fm[0][10][4], f1i = fm[0][10][5];
        float A8r[8], A8i[8];
#pragma unroll
        for (int rr = 0; rr < 8; ++rr) {
            int s = ((rr >> 1) ^ (rr >> 2)) & 1;
            CMUL(A8r[rr], A8i[rr], s ? f1r : f0r, s ? f1i : f0i, A4r[rr & 3], A4i[rr & 3]);
        }
        // H[r2 + 2*r3] = v9[r2^r3] * v8[r3^L0]
        float n0r = fm[0][9][0], n0i = fm[0][9][1];
        float n1r = fm[0][9][4], n1i = fm[0][9][5];
        const float* m8a = &fm[0][8][L0 ? 4 : 0];
        const float* m8b = &fm[0][8][L0 ? 0 : 4];
        float Hr[4], Hi[4];
        CMUL(Hr[0], Hi[0], n0r, n0i, m8a[0], m8a[1]);   // r2=0,r3=0
        CMUL(Hr[1], Hi[1], n1r, n1i, m8a[0], m8a[1]);   // r2=1,r3=0
        CMUL(Hr[2], Hi[2], n1r, n1i, m8b[0], m8b[1]);   // r2=0,r3=1
        CMUL(Hr[3], Hi[3], n0r, n0i, m8b[0], m8b[1]);   // r2=1,r3=1
#pragma unroll
        for (int r = 0; r < 16; ++r) {
            int h = ((r >> 2) & 1) + 2 * (r >> 3);
            CMUL(Ar[r], Ai[r], Hr[h], Hi[h], A8r[r & 7], A8i[r & 7]);
        }
    }

    // scalar 2x2 gate: 4 exprs x (1 mul + 3 fma), negs fold into VOP3 modifiers
#define GATE2(r0c, r1c)                                                       \
    {                                                                         \
        float a0r = Ar[r0c], a0i = Ai[r0c], a1r = Ar[r1c], a1i = Ai[r1c];     \
        Ar[r0c] = u00r * a0r - u00i * a0i + u01r * a1r - u01i * a1i;          \
        Ai[r0c] = u00r * a0i + u00i * a0r + u01r * a1i + u01i * a1r;          \
        Ar[r1c] = u10r * a0r - u10i * a0i + u11r * a1r - u11i * a1i;          \
        Ai[r1c] = u10r * a0i + u10i * a0r + u11r * a1i + u11i * a1r;          \
    }
#define ERA(QOF)                                                              \
    _Pragma("unroll")                                                         \
    for (int j = 0; j < 4; ++j) {                                             \
        const float* g = fm[1][(QOF) - j];                                    \
        float u00r = g[0], u00i = g[1], u01r = g[2], u01i = g[3];             \
        float u10r = g[4], u10i = g[5], u11r = g[6], u11i = g[7];             \
        _Pragma("unroll")                                                     \
        for (int r0 = 0; r0 < 16; ++r0) {                                     \
            if (r0 & (1 << j)) continue;                                      \
            GATE2(r0, r0 | (1 << j));                                         \
        }                                                                     \
    }

    // ==== gates wires 11..8 (Q0 reg bit j <-> wire 11-j) ====
    ERA(11)

    // ==== T1: Q0 -> Q1 (wave-private slots under SL': no barrier) ====
#pragma unroll
    for (int r = 0; r < 16; ++r) sc[rbase ^ r] = (v2){Ar[r], Ai[r]};
#pragma unroll
    for (int r = 0; r < 16; ++r) {
        v2 tv = sc[q1i ^ ((r << 4) ^ r)];
        Ar[r] = tv.x; Ai[r] = tv.y;
    }

    // ==== gates wires 7..4 (Q1 reg bit j <-> wire 7-j) ====
    ERA(7)

    // ==== T2: Q1 -> Q2 (cross-wave) ====
#pragma unroll
    for (int r = 0; r < 16; ++r) sc[q1i ^ ((r << 4) ^ r)] = (v2){Ar[r], Ai[r]};
    __syncthreads();   // [barrier 2]
#pragma unroll
    for (int r = 0; r < 16; ++r) {
        v2 tv = sc[q2s ^ (r << 8)];
        Ar[r] = tv.x; Ai[r] = tv.y;
    }

    // ==== gates wires 3..0 (Q2 reg bit j <-> wire 3-j) ====
    ERA(3)

    // ==== epilogue: ring2 folded into signs (R8/R9-verified masks) ====
    float A7 = 0.f, AC = 0.f, AE = 0.f, AFv = 0.f;
#pragma unroll
    for (int r = 0; r < 16; ++r) {
        float p = Ar[r] * Ar[r] + Ai[r] * Ai[r];
        A7  += par12(r & 0x7) ? -p : p;
        AC  += par12(r & 0xC) ? -p : p;
        AE  += par12(r & 0xE) ? -p : p;
        AFv += par12(r & 0xF) ? -p : p;
    }
#define SSTG(X, SM, OFF) { float y_ = __uint_as_float(__float_as_uint(X) ^ (SM)); X = y_ + __shfl_xor(y_, OFF, 64); }
#define PSTG(X, OFF)     { X += __shfl_xor(X, OFF, 64); }
    float F = AFv, P = AFv;
    SSTG(F, sm5, 32); PSTG(P, 32); float C20 = F;
    SSTG(F, sm4, 16); PSTG(P, 16); PSTG(C20, 16); float C30 = F;
    SSTG(F, sm3, 8);  PSTG(P, 8);  PSTG(C20, 8);  PSTG(C30, 8);  float C38 = F;
    SSTG(F, sm2, 4);  PSTG(P, 4);  PSTG(C20, 4);  PSTG(C30, 4);  PSTG(C38, 4); float C3C = F;
    SSTG(F, sm1, 2);  PSTG(P, 2);  PSTG(C20, 2);  PSTG(C30, 2);  PSTG(C38, 2); PSTG(C3C, 2); float C3E = F;
    SSTG(F, sm0, 1);  PSTG(P, 1);  PSTG(C20, 1);  PSTG(C30, 1);  PSTG(C38, 1); PSTG(C3C, 1); PSTG(C3E, 1);
    float S7 = A7;
    SSTG(S7, sm5, 32); SSTG(S7, sm4, 16); SSTG(S7, sm3, 8); SSTG(S7, sm2, 4); SSTG(S7, sm1, 2); SSTG(S7, sm0, 1);
    float SC = AC, SE = AE;
    PSTG(SC, 32); PSTG(SC, 16); PSTG(SC, 8); PSTG(SC, 4); PSTG(SC, 2); PSTG(SC, 1);
    PSTG(SE, 32); PSTG(SE, 16); PSTG(SE, 8); PSTG(SE, 4); PSTG(SE, 2); PSTG(SE, 1);
#undef SSTG
#undef PSTG
    const int pWv = Wv0 ^ Wv1;
    if (L == 0) {
        red[Wv][0]  = pWv ? -S7 : S7;
        red[Wv][1]  = SC;
        red[Wv][2]  = SE;
        red[Wv][3]  = P;
        red[Wv][4]  = Wv1 ? -P : P;
        red[Wv][5]  = pWv ? -P : P;
        red[Wv][6]  = pWv ? -C20 : C20;
        red[Wv][7]  = pWv ? -C30 : C30;
        red[Wv][8]  = pWv ? -C38 : C38;
        red[Wv][9]  = pWv ? -C3C : C3C;
        red[Wv][10] = pWv ? -C3E : C3E;
        red[Wv][11] = pWv ? -F   : F;
    }
    __syncthreads();   // [barrier 3]
    if (t < NQ) out[b * NQ + t] = red[0][t] + red[1][t] + red[2][t] + red[3][t];
}

extern "C" void kernel_launch(void* const* d_in, const int* in_sizes, int n_in,
                              void* d_out, int out_size, void* d_ws, size_t ws_size,
                              hipStream_t stream) {
    int xi = 0, wi = 1;
    if (n_in >= 2 && in_sizes[1] > in_sizes[0]) { xi = 1; wi = 0; }
    const float* x = (const float*)d_in[xi];
    const float* w = (const float*)d_in[wi];
    float* out = (float*)d_out;
    const int B = in_sizes[xi] / NQ;   // 1024
    qsim_kernel<<<B, NT, 0, stream>>>(x, w, out);
}

// Round 12
// 68.518 us; speedup vs baseline: 1.0777x; 1.0777x over previous
//
#include <hip/hip_runtime.h>

#define NQ 12
#define NT 256   // 4 waves per block; one batch element per block; 16 amps/thread

typedef float v2 __attribute__((ext_vector_type(2)));

// ---------- GF(2)-linear index machinery (HW-verified R4..R9) ----------
__host__ __device__ constexpr int par12(int v) {
    v ^= v >> 8; v ^= v >> 4; v ^= v >> 2; v ^= v >> 1; return v & 1;
}
// LDS slot swizzle (R9-measured configuration).
__host__ __device__ constexpr int SL(int i) { return i ^ ((i >> 5) & 31); }

__device__ __forceinline__ v2 cmadd(v2 c, v2 a, v2 acc) {
    acc += c.x * a;
    v2 j; j.x = -a.y; j.y = a.x;
    acc += c.y * j;
    return acc;
}
__device__ __forceinline__ v2 cmul(v2 c, v2 a) { return cmadd(c, a, (v2){0.f, 0.f}); }
__device__ __forceinline__ void gate2(v2& A0, v2& A1, v2 u00, v2 u01, v2 u10, v2 u11) {
    v2 n0 = cmadd(u01, A1, cmul(u00, A0));
    v2 n1 = cmadd(u11, A1, cmul(u10, A0));
    A0 = n0; A1 = n1;
}
__device__ __forceinline__ v2 sel2(v2 a, v2 b, int c) { return c ? b : a; }

template <int ITERS>
__global__ __launch_bounds__(NT, 4) void qsim_kernel(
    const float* __restrict__ x,   // (B, 12) fp32
    const float* __restrict__ w,   // (2, 12, 3) fp32
    float* __restrict__ out)       // (B, 12) fp32
{
    __shared__ v2 sc[4096];                       // 32 KB state scratch
    __shared__ __align__(16) float fm[2][NQ][8];  // fused U = Rot*RY
    __shared__ float red[4][NQ];

    const int t  = threadIdx.x;
    const int L  = t & 63;
    const int Wv = t >> 6;        // wave id 0..3
    const int b  = blockIdx.x;

    // ---- fused gate matrices U = Rot(phi,theta,omega) * RY(x_q) ----
    if (t < 2 * NQ) {
        int l = t / NQ, q = t % NQ;
        float hy = 0.5f * x[b * NQ + q];
        float cy = cosf(hy), sy = sinf(hy);
        const float* wp = w + (l * NQ + q) * 3;
        float phi = wp[0], the = wp[1], om = wp[2];
        float c = cosf(0.5f * the), s = sinf(0.5f * the);
        float al = 0.5f * (phi + om), be = 0.5f * (phi - om);
        float ca = cosf(al), sa = sinf(al), cb = cosf(be), sb = sinf(be);
        float r00r =  ca * c, r00i = -sa * c;
        float r01r = -cb * s, r01i = -sb * s;
        float r10r =  cb * s, r10i = -sb * s;
        float r11r =  ca * c, r11i =  sa * c;
        float* m = fm[l][q];
        m[0] =  r00r * cy + r01r * sy;  m[1] =  r00i * cy + r01i * sy;  // U00
        m[2] = -r00r * sy + r01r * cy;  m[3] = -r00i * sy + r01i * cy;  // U01
        m[4] =  r10r * cy + r11r * sy;  m[5] =  r10i * cy + r11i * sy;  // U10
        m[6] = -r10r * sy + r11r * cy;  m[7] = -r10i * sy + r11i * cy;  // U11
    }

    // ---- era bases (R8-verified patterns) ----
    const int g0    = (Wv << 10) | (L << 4);
    const int rbase = SL(g0);                              // Q0 slot base
    const int q1i   = (Wv << 10) | ((L >> 4) << 8) | (L & 15);
    const int q1b   = SL(q1i);
    const int q2t   = (Wv << 6) | L;
    const int q2b   = q2t ^ ((q2t >> 5) & 31);
    const int L0 = L & 1, Wv0 = Wv & 1, Wv1 = Wv >> 1;
    // epilogue sign-flip masks per lane bit
    unsigned sm0 = (L & 1)  ? 0x80000000u : 0u;
    unsigned sm1 = (L & 2)  ? 0x80000000u : 0u;
    unsigned sm2 = (L & 4)  ? 0x80000000u : 0u;
    unsigned sm3 = (L & 8)  ? 0x80000000u : 0u;
    unsigned sm4 = (L & 16) ? 0x80000000u : 0u;
    unsigned sm5 = (L & 32) ? 0x80000000u : 0u;

    __syncthreads();   // fm ready  [barrier 1]

    for (int it = 0; it < ITERS; ++it) {
        // ==== post-ring1 state built DIRECTLY in registers ====
        // amp(i) = prod_q v_q[x_{11-q}], x = ringInv(i), i = (Wv<<10)|(L<<4)|r.
        v2 A[16];
        {
            v2 C = sel2(*(const v2*)&fm[0][7][0], *(const v2*)&fm[0][7][4], (L ^ (L >> 1)) & 1);
            C = cmul(sel2(*(const v2*)&fm[0][6][0], *(const v2*)&fm[0][6][4], ((L >> 1) ^ (L >> 2)) & 1), C);
            C = cmul(sel2(*(const v2*)&fm[0][5][0], *(const v2*)&fm[0][5][4], ((L >> 2) ^ (L >> 3)) & 1), C);
            C = cmul(sel2(*(const v2*)&fm[0][4][0], *(const v2*)&fm[0][4][4], ((L >> 3) ^ (L >> 4)) & 1), C);
            C = cmul(sel2(*(const v2*)&fm[0][3][0], *(const v2*)&fm[0][3][4], ((L >> 4) ^ (L >> 5)) & 1), C);
            C = cmul(sel2(*(const v2*)&fm[0][2][0], *(const v2*)&fm[0][2][4], ((L >> 5) ^ Wv0) & 1), C);
            v2 v1a = sel2(*(const v2*)&fm[0][1][0], *(const v2*)&fm[0][1][4], Wv0 ^ Wv1);
            v2 v1b = sel2(*(const v2*)&fm[0][1][0], *(const v2*)&fm[0][1][4], Wv0 ^ Wv1 ^ 1);
            v2 v0a = sel2(*(const v2*)&fm[0][0][0], *(const v2*)&fm[0][0][4], Wv1);
            v2 v0b = sel2(*(const v2*)&fm[0][0][0], *(const v2*)&fm[0][0][4], Wv1 ^ 1);
            v2 A2[2];
            A2[0] = cmul(C, cmul(v1a, v0a));
            A2[1] = cmul(C, cmul(v1b, v0b));
            v2 e0 = *(const v2*)&fm[0][11][0], e1 = *(const v2*)&fm[0][11][4];
            v2 A4[4];
            A4[0] = cmul(e0, A2[0]); A4[1] = cmul(e1, A2[1]);   // r1=0
            A4[2] = cmul(e1, A2[0]); A4[3] = cmul(e0, A2[1]);   // r1=1
            v2 f0 = *(const v2*)&fm[0][10][0], f1 = *(const v2*)&fm[0][10][4];
            v2 A8[8];
#pragma unroll
            for (int rr = 0; rr < 8; ++rr) {
                int r1 = (rr >> 1) & 1, r2 = (rr >> 2) & 1;
                A8[rr] = cmul((r1 ^ r2) ? f1 : f0, A4[rr & 3]);
            }
            v2 n0 = *(const v2*)&fm[0][9][0], n1 = *(const v2*)&fm[0][9][4];
            v2 m8a = sel2(*(const v2*)&fm[0][8][0], *(const v2*)&fm[0][8][4], L0);
            v2 m8b = sel2(*(const v2*)&fm[0][8][0], *(const v2*)&fm[0][8][4], L0 ^ 1);
            v2 H[4];
            H[0] = cmul(n0, m8a);  // r2=0,r3=0
            H[1] = cmul(n1, m8a);  // r2=1,r3=0
            H[2] = cmul(n1, m8b);  // r2=0,r3=1
            H[3] = cmul(n0, m8b);  // r2=1,r3=1
#pragma unroll
            for (int r = 0; r < 16; ++r)
                A[r] = cmul(H[((r >> 2) & 1) + 2 * (r >> 3)], A8[r & 7]);
        }

        // ==== gates wires 11..8 (Q0 reg bit j <-> wire 11-j) ====
#pragma unroll
        for (int j = 0; j < 4; ++j) {
            const int q = 11 - j;
            float4 lo = *(const float4*)&fm[1][q][0], hi = *(const float4*)&fm[1][q][4];
            v2 u00 = {lo.x, lo.y}, u01 = {lo.z, lo.w}, u10 = {hi.x, hi.y}, u11 = {hi.z, hi.w};
#pragma unroll
            for (int r0 = 0; r0 < 16; ++r0) {
                if (r0 & (1 << j)) continue;
                gate2(A[r0], A[r0 | (1 << j)], u00, u01, u10, u11);
            }
        }

        // ==== T1: Q0 -> Q1 (same-wave slot reuse: DS in-order, no barrier) ====
#pragma unroll
        for (int r = 0; r < 16; ++r) sc[rbase ^ r] = A[r];
#pragma unroll
        for (int r = 0; r < 16; ++r) A[r] = sc[q1b ^ ((r << 4) ^ (r >> 1))];

        // ==== gates wires 7..4 (Q1 reg bit j <-> wire 7-j) ====
#pragma unroll
        for (int j = 0; j < 4; ++j) {
            const int q = 7 - j;
            float4 lo = *(const float4*)&fm[1][q][0], hi = *(const float4*)&fm[1][q][4];
            v2 u00 = {lo.x, lo.y}, u01 = {lo.z, lo.w}, u10 = {hi.x, hi.y}, u11 = {hi.z, hi.w};
#pragma unroll
            for (int r0 = 0; r0 < 16; ++r0) {
                if (r0 & (1 << j)) continue;
                gate2(A[r0], A[r0 | (1 << j)], u00, u01, u10, u11);
            }
        }

        // ==== T2: Q1 -> Q2 (cross-wave) ====
#pragma unroll
        for (int r = 0; r < 16; ++r) sc[q1b ^ ((r << 4) ^ (r >> 1))] = A[r];
        __syncthreads();   // [barrier 2]
#pragma unroll
        for (int r = 0; r < 16; ++r) A[r] = sc[q2b ^ ((r << 8) ^ ((r & 3) << 3))];

        // ==== gates wires 3..0 (Q2 reg bit j <-> wire 3-j) ====
#pragma unroll
        for (int j = 0; j < 4; ++j) {
            const int q = 3 - j;
            float4 lo = *(const float4*)&fm[1][q][0], hi = *(const float4*)&fm[1][q][4];
            v2 u00 = {lo.x, lo.y}, u01 = {lo.z, lo.w}, u10 = {hi.x, hi.y}, u11 = {hi.z, hi.w};
#pragma unroll
            for (int r0 = 0; r0 < 16; ++r0) {
                if (r0 & (1 << j)) continue;
                gate2(A[r0], A[r0 | (1 << j)], u00, u01, u10, u11);
            }
        }

        // ==== epilogue: ring2 folded into signs (R8-verified masks) ====
        float A7 = 0.f, AC = 0.f, AE = 0.f, AFv = 0.f;
#pragma unroll
        for (int r = 0; r < 16; ++r) {
            float p = A[r].x * A[r].x + A[r].y * A[r].y;
            A7  += par12(r & 0x7) ? -p : p;
            AC  += par12(r & 0xC) ? -p : p;
            AE  += par12(r & 0xE) ? -p : p;
            AFv += par12(r & 0xF) ? -p : p;
        }
        // shared-prefix Walsh butterflies over lane bits 5..0
#define SSTG(X, SM, OFF) { float y_ = __uint_as_float(__float_as_uint(X) ^ (SM)); X = y_ + __shfl_xor(y_, OFF, 64); }
#define PSTG(X, OFF)     { X += __shfl_xor(X, OFF, 64); }
        float F = AFv, P = AFv;
        SSTG(F, sm5, 32); PSTG(P, 32); float C20 = F;
        SSTG(F, sm4, 16); PSTG(P, 16); PSTG(C20, 16); float C30 = F;
        SSTG(F, sm3, 8);  PSTG(P, 8);  PSTG(C20, 8);  PSTG(C30, 8);  float C38 = F;
        SSTG(F, sm2, 4);  PSTG(P, 4);  PSTG(C20, 4);  PSTG(C30, 4);  PSTG(C38, 4); float C3C = F;
        SSTG(F, sm1, 2);  PSTG(P, 2);  PSTG(C20, 2);  PSTG(C30, 2);  PSTG(C38, 2); PSTG(C3C, 2); float C3E = F;
        SSTG(F, sm0, 1);  PSTG(P, 1);  PSTG(C20, 1);  PSTG(C30, 1);  PSTG(C38, 1); PSTG(C3C, 1); PSTG(C3E, 1);
        float S7 = A7;
        SSTG(S7, sm5, 32); SSTG(S7, sm4, 16); SSTG(S7, sm3, 8); SSTG(S7, sm2, 4); SSTG(S7, sm1, 2); SSTG(S7, sm0, 1);
        float SC = AC, SE = AE;
        PSTG(SC, 32); PSTG(SC, 16); PSTG(SC, 8); PSTG(SC, 4); PSTG(SC, 2); PSTG(SC, 1);
        PSTG(SE, 32); PSTG(SE, 16); PSTG(SE, 8); PSTG(SE, 4); PSTG(SE, 2); PSTG(SE, 1);
#undef SSTG
#undef PSTG
        const int pWv = Wv0 ^ Wv1;
        if (L == 0) {
            red[Wv][0]  = pWv ? -S7 : S7;
            red[Wv][1]  = SC;
            red[Wv][2]  = SE;
            red[Wv][3]  = P;
            red[Wv][4]  = Wv1 ? -P : P;
            red[Wv][5]  = pWv ? -P : P;
            red[Wv][6]  = pWv ? -C20 : C20;
            red[Wv][7]  = pWv ? -C30 : C30;
            red[Wv][8]  = pWv ? -C38 : C38;
            red[Wv][9]  = pWv ? -C3C : C3C;
            red[Wv][10] = pWv ? -C3E : C3E;
            red[Wv][11] = pWv ? -F   : F;
        }
        __syncthreads();   // [barrier 3]
        if (t < NQ) out[b * NQ + t] = red[0][t] + red[1][t] + red[2][t] + red[3][t];
        if (ITERS > 1) __syncthreads();   // red reuse safety across iters
    }
}

extern "C" void kernel_launch(void* const* d_in, const int* in_sizes, int n_in,
                              void* d_out, int out_size, void* d_ws, size_t ws_size,
                              hipStream_t stream) {
    int xi = 0, wi = 1;
    if (n_in >= 2 && in_sizes[1] > in_sizes[0]) { xi = 1; wi = 0; }
    const float* x = (const float*)d_in[xi];
    const float* w = (const float*)d_in[wi];
    float* out = (float*)d_out;
    const int B = in_sizes[xi] / NQ;   // 1024
    // R9's measured-fast instantiation, diagnostic launch removed.
    qsim_kernel<1><<<B, NT, 0, stream>>>(x, w, out);
}

// Round 13
// 61.750 us; speedup vs baseline: 1.1959x; 1.1096x over previous
//
#include <hip/hip_runtime.h>

#define NQ 12
#define NT 64   // one wave per block; one batch element per block

// ---------------------------------------------------------------------------
// Transfer-matrix evaluation of the circuit (wire-space, ring-verified maps):
//   psi1(c) = v_0[c0^c11] * v_1[c1^c0^c11] * prod_{q=2..11} v_q[cq^c(q-1)]
//   psi2(d) = sum_c prod_q U_q[d_q,c_q] psi1(c)
//   <Z_q*>  = sum_d sign_q*(d) |psi2(d)|^2,  sign from ring2 prefix parities:
//             mask(q*>=1) = d_0..d_q*,  mask(0) = d_1..d_11.
// Chain: sites 2..10 -> 4x4 A_q (unsigned d-sum) / B_q (signed); site 1 and
// v_0 fold into a signed left vector gS(s,s'); sites 0,11 fold into right
// vectors Rv with 3 sign variants. Verified symbolically on identity and
// RY(pi) instances against direct permutation evaluation.
// ---------------------------------------------------------------------------

struct cpx { float x, y; };
__device__ __forceinline__ cpx cmul(cpx a, cpx b) {
    return { a.x * b.x - a.y * b.y, a.x * b.y + a.y * b.x };
}
__device__ __forceinline__ cpx cmulc(cpx a, cpx b) {   // a * conj(b)
    return { a.x * b.x + a.y * b.y, a.y * b.x - a.x * b.y };
}
__device__ __forceinline__ cpx cadd(cpx a, cpx b) { return { a.x + b.x, a.y + b.y }; }
__device__ __forceinline__ cpx csub(cpx a, cpx b) { return { a.x - b.x, a.y - b.y }; }
__device__ __forceinline__ cpx shflc(cpx a, int lane) {
    cpx r; r.x = __shfl(a.x, lane, 64); r.y = __shfl(a.y, lane, 64); return r;
}

__global__ __launch_bounds__(NT) void qsim_kernel(
    const float* __restrict__ x,   // (B, 12) fp32
    const float* __restrict__ w,   // (2, 12, 3) fp32
    float* __restrict__ out)       // (B, 12) fp32
{
    __shared__ float fm[2][NQ][8];     // fused U = Rot*RY (verified build)
    __shared__ cpx Amat[9][16], Bmat[9][16];   // sites q=2..10
    __shared__ cpx gS[4][4];           // [2s+s'][(c1,c1')], LW folded, signed d1
    __shared__ cpx h0U[4], h0S[4], h11U[4], h11S[4];
    __shared__ cpx Rv[3][4][4];        // [variant][2s+s'][(c10,c10')]
    __shared__ cpx PBc[11][16];        // PB_k = B_2..B_k (PB_1 = I)
    __shared__ cpx SAc[12][16];        // SA_k = A_k..A_10 (SA_11 = I)
    __shared__ float sval[48];

    const int t = threadIdx.x;
    const int b = blockIdx.x;

    // ---- fused gate matrices U = Rot(phi,theta,omega) * RY(x_q) (verified) ----
    if (t < 2 * NQ) {
        int l = t / NQ, q = t % NQ;
        float hy = 0.5f * x[b * NQ + q];
        float cy = cosf(hy), sy = sinf(hy);
        const float* wp = w + (l * NQ + q) * 3;
        float phi = wp[0], the = wp[1], om = wp[2];
        float c = cosf(0.5f * the), s = sinf(0.5f * the);
        float al = 0.5f * (phi + om), be = 0.5f * (phi - om);
        float ca = cosf(al), sa = sinf(al), cb = cosf(be), sb = sinf(be);
        float r00r =  ca * c, r00i = -sa * c;
        float r01r = -cb * s, r01i = -sb * s;
        float r10r =  cb * s, r10i = -sb * s;
        float r11r =  ca * c, r11i =  sa * c;
        float* m = fm[l][q];
        m[0] =  r00r * cy + r01r * sy;  m[1] =  r00i * cy + r01i * sy;  // U00
        m[2] = -r00r * sy + r01r * cy;  m[3] = -r00i * sy + r01i * cy;  // U01
        m[4] =  r10r * cy + r11r * sy;  m[5] =  r10i * cy + r11i * sy;  // U10
        m[6] = -r10r * sy + r11r * cy;  m[7] = -r10i * sy + r11i * cy;  // U11
    }
    __syncthreads();

    // v_q[bit] = layer-1 column 0 (verified product-state usage); U_q = layer-2
    auto Vq = [&](int q, int bit) -> cpx {
        const float* m = &fm[0][q][bit ? 4 : 0]; return { m[0], m[1] };
    };
    auto Uq = [&](int q, int d, int c) -> cpx {
        const float* m = &fm[1][q][4 * d + 2 * c]; return { m[0], m[1] };
    };

    // ---- site objects: A/B (q=2..10), gS (site 1 + v0 weight), h (sites 0,11) ----
    if (t < 16) {
        const int a = (t >> 3) & 1, ap = (t >> 2) & 1, c = (t >> 1) & 1, cp = t & 1;
        for (int q = 2; q <= 10; ++q) {
            // T_q(d)[a,c] = v_q[c^a] * U_q[d,c]
            cpx t0 = cmul(Vq(q, c ^ a),  Uq(q, 0, c));
            cpx t1 = cmul(Vq(q, c ^ a),  Uq(q, 1, c));
            cpx p0 = cmul(Vq(q, cp ^ ap), Uq(q, 0, cp));
            cpx p1 = cmul(Vq(q, cp ^ ap), Uq(q, 1, cp));
            cpx e0 = cmulc(t0, p0), e1 = cmulc(t1, p1);
            Amat[q - 2][t] = cadd(e0, e1);
            Bmat[q - 2][t] = csub(e0, e1);
        }
        // gS[(s,s')][(c1,c1')] = v0[s]*conj(v0[s']) * sum_d (-1)^d l(d)*conj(l'(d))
        const int s = a, sp = ap, cc = c, ccp = cp;
        cpx l0 = cmul(Uq(1, 0, cc),  Vq(1, cc ^ s));
        cpx l1 = cmul(Uq(1, 1, cc),  Vq(1, cc ^ s));
        cpx m0 = cmul(Uq(1, 0, ccp), Vq(1, ccp ^ sp));
        cpx m1 = cmul(Uq(1, 1, ccp), Vq(1, ccp ^ sp));
        cpx g  = csub(cmulc(l0, m0), cmulc(l1, m1));
        cpx lw = cmulc(Vq(0, s), Vq(0, sp));
        gS[2 * s + sp][2 * cc + ccp] = cmul(g, lw);
    }
    if (t < 4) {
        const int c0 = t >> 1, c0p = t & 1;
        cpx a0 = cmulc(Uq(0, 0, c0),  Uq(0, 0, c0p));
        cpx a1 = cmulc(Uq(0, 1, c0),  Uq(0, 1, c0p));
        h0U[t] = cadd(a0, a1);  h0S[t] = csub(a0, a1);
        cpx b0 = cmulc(Uq(11, 0, c0),  Uq(11, 0, c0p));
        cpx b1 = cmulc(Uq(11, 1, c0),  Uq(11, 1, c0p));
        h11U[t] = cadd(b0, b1);  h11S[t] = csub(b0, b1);
    }
    __syncthreads();

    // ---- right boundary vectors: sites 0 & 11 + v_11 wrap factor ----
    // variants: V0 = (h0S, h11U) for q*=1..10; V1 = (h0U, h11S) for q*=0;
    //           V2 = (h0S, h11S) for q*=11.
    if (t < 16) {
        const int s = (t >> 3) & 1, sp = (t >> 2) & 1, c10 = (t >> 1) & 1, c10p = t & 1;
        for (int V = 0; V < 3; ++V) {
            const cpx* h0  = (V == 1) ? h0U  : h0S;
            const cpx* h11 = (V == 0) ? h11U : h11S;
            cpx acc = { 0.f, 0.f };
            for (int c0 = 0; c0 < 2; ++c0)
                for (int c0p = 0; c0p < 2; ++c0p) {
                    cpx term = cmul(h0[2 * c0 + c0p], h11[2 * (c0 ^ s) + (c0p ^ sp)]);
                    term = cmul(term, Vq(11, c0 ^ s ^ c10));
                    term = cmulc(term, Vq(11, c0p ^ sp ^ c10p));
                    acc = cadd(acc, term);
                }
            Rv[V][2 * s + sp][2 * c10 + c10p] = acc;
        }
    }
    __syncthreads();

    // ---- chain prefix/suffix products (4x4, 16 lanes = entries) ----
    if (t < 16) {
        const int R = t >> 2, C = t & 3;
        cpx cur = { (R == C) ? 1.f : 0.f, 0.f };
        PBc[1][t] = cur;
        for (int k = 2; k <= 10; ++k) {                 // PB_k = PB_{k-1} * B_k
            cpx nv = { 0.f, 0.f };
            for (int K = 0; K < 4; ++K)
                nv = cadd(nv, cmul(shflc(cur, 4 * R + K), Bmat[k - 2][4 * K + C]));
            cur = nv;
            PBc[k][t] = cur;
        }
        cur = { (R == C) ? 1.f : 0.f, 0.f };
        SAc[11][t] = cur;
        for (int k = 10; k >= 2; --k) {                 // SA_k = A_k * SA_{k+1}
            cpx nv = { 0.f, 0.f };
            for (int K = 0; K < 4; ++K)
                nv = cadd(nv, cmul(Amat[k - 2][4 * R + K], shflc(cur, 4 * K + C)));
            cur = nv;
            SAc[k][t] = cur;
        }
    }
    __syncthreads();

    // ---- finals: <Z_q*> = sum_{s,s'} gS * PB_kk * SA_{kk+1} * Rv ----
    if (t < 16) {
        for (int pi = t; pi < 48; pi += 16) {
            const int qq = pi >> 2, ssi = pi & 3;
            const int kk = (qq == 0 || qq == 11) ? 10 : qq;
            const int V  = (qq == 0) ? 1 : ((qq == 11) ? 2 : 0);
            cpx rowL[4], colR[4];
            for (int K = 0; K < 4; ++K) {
                cpx acc = { 0.f, 0.f };
                for (int R = 0; R < 4; ++R)
                    acc = cadd(acc, cmul(gS[ssi][R], PBc[kk][4 * R + K]));
                rowL[K] = acc;
                cpx acc2 = { 0.f, 0.f };
                for (int C = 0; C < 4; ++C)
                    acc2 = cadd(acc2, cmul(SAc[kk + 1][4 * K + C], Rv[V][ssi][C]));
                colR[K] = acc2;
            }
            cpx val = { 0.f, 0.f };
            for (int K = 0; K < 4; ++K) val = cadd(val, cmul(rowL[K], colR[K]));
            sval[pi] = val.x;   // result is real up to fp noise
        }
    }
    __syncthreads();
    if (t < NQ)
        out[b * NQ + t] = sval[4 * t] + sval[4 * t + 1] + sval[4 * t + 2] + sval[4 * t + 3];
}

extern "C" void kernel_launch(void* const* d_in, const int* in_sizes, int n_in,
                              void* d_out, int out_size, void* d_ws, size_t ws_size,
                              hipStream_t stream) {
    int xi = 0, wi = 1;
    if (n_in >= 2 && in_sizes[1] > in_sizes[0]) { xi = 1; wi = 0; }
    const float* x = (const float*)d_in[xi];
    const float* w = (const float*)d_in[wi];
    float* out = (float*)d_out;
    const int B = in_sizes[xi] / NQ;   // 1024
    qsim_kernel<<<B, NT, 0, stream>>>(x, w, out);
}

// Round 14
// 60.861 us; speedup vs baseline: 1.2133x; 1.0146x over previous
//
#include <hip/hip_runtime.h>

#define NQ 12
#define NT 64    // one wave per block
#define EPB 4    // elements per block: one per 16-lane group

// ---------------------------------------------------------------------------
// Transfer-matrix evaluation (math identical to R13, which passed with
// absmax 4.88e-4; only the lane/block mapping changed: 4 elements per wave,
// entry u = lane&15 within group g = lane>>4).
// ---------------------------------------------------------------------------

struct cpx { float x, y; };
__device__ __forceinline__ cpx cmul(cpx a, cpx b) {
    return { a.x * b.x - a.y * b.y, a.x * b.y + a.y * b.x };
}
__device__ __forceinline__ cpx cmulc(cpx a, cpx b) {   // a * conj(b)
    return { a.x * b.x + a.y * b.y, a.y * b.x - a.x * b.y };
}
__device__ __forceinline__ cpx cadd(cpx a, cpx b) { return { a.x + b.x, a.y + b.y }; }
__device__ __forceinline__ cpx csub(cpx a, cpx b) { return { a.x - b.x, a.y - b.y }; }
__device__ __forceinline__ cpx shflc(cpx a, int lane) {
    cpx r; r.x = __shfl(a.x, lane, 64); r.y = __shfl(a.y, lane, 64); return r;
}

__global__ __launch_bounds__(NT) void qsim_kernel(
    const float* __restrict__ x,   // (B, 12) fp32
    const float* __restrict__ w,   // (2, 12, 3) fp32
    float* __restrict__ out)       // (B, 12) fp32
{
    __shared__ float fm[EPB][2][NQ][8];
    __shared__ cpx Amat[EPB][9][16], Bmat[EPB][9][16];
    __shared__ cpx gS[EPB][4][4];
    __shared__ cpx h0U[EPB][4], h0S[EPB][4], h11U[EPB][4], h11S[EPB][4];
    __shared__ cpx Rv[EPB][3][4][4];
    __shared__ cpx PBc[EPB][11][16];
    __shared__ cpx SAc[EPB][12][16];
    __shared__ float sval[EPB][48];

    const int t    = threadIdx.x;
    const int g    = t >> 4;       // group = element slot in block
    const int u    = t & 15;       // entry index within group
    const int base = t & 48;       // shfl base lane of the group
    const int b0   = blockIdx.x * EPB;

    // ---- fused gate matrices for all 4 elements: 96 tasks over 64 lanes ----
    for (int task = t; task < EPB * 2 * NQ; task += NT) {
        int e = task / (2 * NQ);
        int rem = task % (2 * NQ);
        int l = rem / NQ, q = rem % NQ;
        float hy = 0.5f * x[(b0 + e) * NQ + q];
        float cy = cosf(hy), sy = sinf(hy);
        const float* wp = w + (l * NQ + q) * 3;
        float phi = wp[0], the = wp[1], om = wp[2];
        float c = cosf(0.5f * the), s = sinf(0.5f * the);
        float al = 0.5f * (phi + om), be = 0.5f * (phi - om);
        float ca = cosf(al), sa = sinf(al), cb = cosf(be), sb = sinf(be);
        float r00r =  ca * c, r00i = -sa * c;
        float r01r = -cb * s, r01i = -sb * s;
        float r10r =  cb * s, r10i = -sb * s;
        float r11r =  ca * c, r11i =  sa * c;
        float* m = fm[e][l][q];
        m[0] =  r00r * cy + r01r * sy;  m[1] =  r00i * cy + r01i * sy;  // U00
        m[2] = -r00r * sy + r01r * cy;  m[3] = -r00i * sy + r01i * cy;  // U01
        m[4] =  r10r * cy + r11r * sy;  m[5] =  r10i * cy + r11i * sy;  // U10
        m[6] = -r10r * sy + r11r * cy;  m[7] = -r10i * sy + r11i * cy;  // U11
    }
    __syncthreads();

    auto Vq = [&](int q, int bit) -> cpx {
        const float* m = &fm[g][0][q][bit ? 4 : 0]; return { m[0], m[1] };
    };
    auto Uq = [&](int q, int d, int c) -> cpx {
        const float* m = &fm[g][1][q][4 * d + 2 * c]; return { m[0], m[1] };
    };

    // ---- site objects (all 64 lanes; entry u of group g) ----
    {
        const int a = (u >> 3) & 1, ap = (u >> 2) & 1, c = (u >> 1) & 1, cp = u & 1;
        for (int q = 2; q <= 10; ++q) {
            cpx t0 = cmul(Vq(q, c ^ a),  Uq(q, 0, c));
            cpx t1 = cmul(Vq(q, c ^ a),  Uq(q, 1, c));
            cpx p0 = cmul(Vq(q, cp ^ ap), Uq(q, 0, cp));
            cpx p1 = cmul(Vq(q, cp ^ ap), Uq(q, 1, cp));
            cpx e0 = cmulc(t0, p0), e1 = cmulc(t1, p1);
            Amat[g][q - 2][u] = cadd(e0, e1);
            Bmat[g][q - 2][u] = csub(e0, e1);
        }
        const int s = a, sp = ap, cc = c, ccp = cp;
        cpx l0 = cmul(Uq(1, 0, cc),  Vq(1, cc ^ s));
        cpx l1 = cmul(Uq(1, 1, cc),  Vq(1, cc ^ s));
        cpx m0 = cmul(Uq(1, 0, ccp), Vq(1, ccp ^ sp));
        cpx m1 = cmul(Uq(1, 1, ccp), Vq(1, ccp ^ sp));
        cpx gg = csub(cmulc(l0, m0), cmulc(l1, m1));
        cpx lw = cmulc(Vq(0, s), Vq(0, sp));
        gS[g][2 * s + sp][2 * cc + ccp] = cmul(gg, lw);
    }
    if (u < 4) {
        const int c0 = u >> 1, c0p = u & 1;
        cpx a0 = cmulc(Uq(0, 0, c0),  Uq(0, 0, c0p));
        cpx a1 = cmulc(Uq(0, 1, c0),  Uq(0, 1, c0p));
        h0U[g][u] = cadd(a0, a1);  h0S[g][u] = csub(a0, a1);
        cpx b0v = cmulc(Uq(11, 0, c0),  Uq(11, 0, c0p));
        cpx b1v = cmulc(Uq(11, 1, c0),  Uq(11, 1, c0p));
        h11U[g][u] = cadd(b0v, b1v);  h11S[g][u] = csub(b0v, b1v);
    }
    __syncthreads();

    // ---- right boundary vectors (3 sign variants) ----
    {
        const int s = (u >> 3) & 1, sp = (u >> 2) & 1, c10 = (u >> 1) & 1, c10p = u & 1;
        for (int V = 0; V < 3; ++V) {
            const cpx* h0  = (V == 1) ? h0U[g]  : h0S[g];
            const cpx* h11 = (V == 0) ? h11U[g] : h11S[g];
            cpx acc = { 0.f, 0.f };
            for (int c0 = 0; c0 < 2; ++c0)
                for (int c0p = 0; c0p < 2; ++c0p) {
                    cpx term = cmul(h0[2 * c0 + c0p], h11[2 * (c0 ^ s) + (c0p ^ sp)]);
                    term = cmul(term, Vq(11, c0 ^ s ^ c10));
                    term = cmulc(term, Vq(11, c0p ^ sp ^ c10p));
                    acc = cadd(acc, term);
                }
            Rv[g][V][2 * s + sp][2 * c10 + c10p] = acc;
        }
    }
    __syncthreads();

    // ---- chain prefix/suffix products (4x4; entry u = (R,C)) ----
    {
        const int R = u >> 2, C = u & 3;
        cpx cur = { (R == C) ? 1.f : 0.f, 0.f };
        PBc[g][1][u] = cur;
        for (int k = 2; k <= 10; ++k) {                 // PB_k = PB_{k-1} * B_k
            cpx nv = { 0.f, 0.f };
            for (int K = 0; K < 4; ++K)
                nv = cadd(nv, cmul(shflc(cur, base + 4 * R + K), Bmat[g][k - 2][4 * K + C]));
            cur = nv;
            PBc[g][k][u] = cur;
        }
        cur = { (R == C) ? 1.f : 0.f, 0.f };
        SAc[g][11][u] = cur;
        for (int k = 10; k >= 2; --k) {                 // SA_k = A_k * SA_{k+1}
            cpx nv = { 0.f, 0.f };
            for (int K = 0; K < 4; ++K)
                nv = cadd(nv, cmul(Amat[g][k - 2][4 * R + K], shflc(cur, base + 4 * K + C)));
            cur = nv;
            SAc[g][k][u] = cur;
        }
    }
    __syncthreads();

    // ---- finals: <Z_q*> = sum_{s,s'} gS * PB_kk * SA_{kk+1} * Rv ----
    for (int pi = u; pi < 48; pi += 16) {
        const int qq = pi >> 2, ssi = pi & 3;
        const int kk = (qq == 0 || qq == 11) ? 10 : qq;
        const int V  = (qq == 0) ? 1 : ((qq == 11) ? 2 : 0);
        cpx rowL[4], colR[4];
        for (int K = 0; K < 4; ++K) {
            cpx acc = { 0.f, 0.f };
            for (int R = 0; R < 4; ++R)
                acc = cadd(acc, cmul(gS[g][ssi][R], PBc[g][kk][4 * R + K]));
            rowL[K] = acc;
            cpx acc2 = { 0.f, 0.f };
            for (int C = 0; C < 4; ++C)
                acc2 = cadd(acc2, cmul(SAc[g][kk + 1][4 * K + C], Rv[g][V][ssi][C]));
            colR[K] = acc2;
        }
        cpx val = { 0.f, 0.f };
        for (int K = 0; K < 4; ++K) val = cadd(val, cmul(rowL[K], colR[K]));
        sval[g][pi] = val.x;   // real up to fp noise
    }
    __syncthreads();

    // ---- write: EPB*NQ = 48 outputs per block ----
    if (t < EPB * NQ) {
        int e = t / NQ, q = t % NQ;
        out[(b0 + e) * NQ + q] =
            sval[e][4 * q] + sval[e][4 * q + 1] + sval[e][4 * q + 2] + sval[e][4 * q + 3];
    }
}

extern "C" void kernel_launch(void* const* d_in, const int* in_sizes, int n_in,
                              void* d_out, int out_size, void* d_ws, size_t ws_size,
                              hipStream_t stream) {
    int xi = 0, wi = 1;
    if (n_in >= 2 && in_sizes[1] > in_sizes[0]) { xi = 1; wi = 0; }
    const float* x = (const float*)d_in[xi];
    const float* w = (const float*)d_in[wi];
    float* out = (float*)d_out;
    const int B = in_sizes[xi] / NQ;   // 1024
    qsim_kernel<<<B / EPB, NT, 0, stream>>>(x, w, out);
}